// Round 11
// baseline (186.379 us; speedup 1.0000x reference)
//
#include <hip/hip_runtime.h>
#include <math.h>

#define EPS  1e-6f
#define DD   256
#define NSUP 5
#define NQ   8
#define SEQ  13
#define L2E  1.44269504088896f
#define LN2  0.693147180559945f
#define NEP  2048            // episodes
#define NROW 16384           // NEP*NQ query rows
#define NCOL 2048            // anchor columns
#define NRG  256             // rowgroups of 64 rows
#define NTB  32              // col-tiles per block (512 cols)

typedef short bf16x8 __attribute__((ext_vector_type(8)));
typedef unsigned short u16x4 __attribute__((ext_vector_type(4)));
typedef float f32x4  __attribute__((ext_vector_type(4)));

__device__ __forceinline__ ushort f2bf(float f) {
  union { float f; unsigned u; } v; v.f = f;
  unsigned r = v.u + 0x7FFFu + ((v.u >> 16) & 1u);   // round-to-nearest-even
  return (ushort)(r >> 16);
}
__device__ __forceinline__ float bf2f(short u) {
  union { unsigned u; float f; } v; v.u = ((unsigned)(unsigned short)u) << 16;
  return v.f;
}

// ---------------------------------------------------------------------------
// prep (r8, proven): anchors/queries in MFMA-fragment-SWIZZLED order; element
// (c,d) -> ushort idx (((c>>4)*8+(d>>5))*64 + ((d>>3)&3)*16 + (c&15))*8+(d&7).
// cb[c] = -log2(e)*(sum(a^2) - 2*eps*sum(a)); row-constant cq cancels.
// Zeroes accum/fincount/rgcount (ws re-poisoned before every call).
// ---------------------------------------------------------------------------
__global__ __launch_bounds__(256) void proto_prep(
    const float* __restrict__ x, float* __restrict__ cb,
    ushort* __restrict__ Asw, ushort* __restrict__ Qsw,
    float* __restrict__ accum, int* __restrict__ fincount,
    int* __restrict__ rgcount) {
  const int tid = threadIdx.x, g = tid >> 6, l = tid & 63;
  const int n = blockIdx.x * 4 + g;
  if (blockIdx.x == 0 && tid == 0) { accum[0] = 0.f; accum[1] = 0.f; fincount[0] = 0; }
  if (tid == 0 && blockIdx.x < NRG) rgcount[blockIdx.x] = 0;

  const float4* xr4 = (const float4*)(x + (size_t)n * SEQ * DD);

  const int d0   = l * 4;
  const int kk   = d0 >> 5, quad = (d0 >> 3) & 3, j = d0 & 7;   // j in {0,4}
  const size_t chunk_d = (size_t)kk * 64 + (size_t)quad * 16;

  float4 a = {0.f, 0.f, 0.f, 0.f};
  #pragma unroll
  for (int s = 0; s < NSUP; ++s) {
    float4 v = xr4[s * 64 + l];
    a.x += v.x; a.y += v.y; a.z += v.z; a.w += v.w;
  }
  a.x *= 0.2f; a.y *= 0.2f; a.z *= 0.2f; a.w *= 0.2f;
  {
    const size_t idx = (((size_t)(n >> 4) * 8) * 64 + chunk_d + (n & 15)) * 8 + j;
    u16x4 o = {f2bf(a.x), f2bf(a.y), f2bf(a.z), f2bf(a.w)};
    *(u16x4*)(Asw + idx) = o;
  }
  float s1 = a.x + a.y + a.z + a.w;
  float s2 = a.x * a.x + a.y * a.y + a.z * a.z + a.w * a.w;
  #pragma unroll
  for (int off = 32; off; off >>= 1) {
    s1 += __shfl_xor(s1, off);
    s2 += __shfl_xor(s2, off);
  }
  if (l == 0) cb[n] = -L2E * (s2 - 2.f * EPS * s1);

  #pragma unroll
  for (int s = 0; s < NQ; ++s) {
    float4 q = xr4[(NSUP + s) * 64 + l];
    const int row = n * NQ + s;
    const size_t idx = (((size_t)(row >> 4) * 8) * 64 + chunk_d + (row & 15)) * 8 + j;
    u16x4 o = {f2bf(q.x), f2bf(q.y), f2bf(q.z), f2bf(q.w)};
    *(u16x4*)(Qsw + idx) = o;
  }
}

// ---------------------------------------------------------------------------
// main: m97-style block-cooperative K-loop. 1024 blocks x 256 threads;
// block = rowgroup (64 rows) x col-quarter (512 cols = 32 tiles). All 4
// waves march the SAME tile stream; each B tile is DMA'd ONCE into
// double-buffered LDS (global_load_lds w16, each wave issues 2 of 8 chunks)
// and read by all waves — B L2 traffic /4 vs per-wave staging, and per-wave
// registers collapse (A-frags 8, no staging bufs) so 4 blocks/CU co-reside
// with independent barriers covering each other's DMA drains.
// Pipeline: dma(t+1) -> compute(t) -> __syncthreads (vmcnt drain).
// Partials per quarter posted via device-scope atomics; LAST arriver
// (rgcount==3) merges quarters in ascending col order, computes label logits
// (bf16 dot, identical rounding), accumulates; counter finalize (r6/r7-
// proven machinery). MFMA layouts (verified): A m=lane&15,k=quad*8+j ;
// B n=lane&15,k=quad*8+j ; C col=lane&15,row=quad*4+reg.
// ---------------------------------------------------------------------------
__global__ __launch_bounds__(256) void proto_main(
    const ushort* __restrict__ Qsw, const ushort* __restrict__ Asw,
    const float* __restrict__ cb, const int* __restrict__ label,
    float* __restrict__ pm, float* __restrict__ ps, int* __restrict__ pb,
    int* __restrict__ rgcount,
    float* __restrict__ accum, int* __restrict__ fincount,
    float* __restrict__ out) {
  const int tid  = threadIdx.x;
  const int wid  = tid >> 6, lane = tid & 63;
  const int quad = lane >> 4, lcol = lane & 15;
  const int rg   = blockIdx.x >> 2;
  const int qq   = blockIdx.x & 3;
  const int r0   = rg * 64;
  const int T0   = qq * NTB;

  __shared__ __align__(16) ushort sB[2][4096];   // double-buffered 8 KB tile
  __shared__ float slab[64];
  __shared__ int   s_old;

  const bf16x8* qb = (const bf16x8*)Qsw;
  const bf16x8* bb = (const bf16x8*)Asw;

  // A fragments for this wave's 16 rows: 8 K-chunks (coalesced loads)
  bf16x8 af[8];
  {
    const size_t base = ((size_t)((r0 >> 4) + wid) * 8) * 64 + lane;
    #pragma unroll
    for (int kk = 0; kk < 8; ++kk) af[kk] = qb[base + (size_t)kk * 64];
  }

  float m[4], s[4];
  int   bi[4];
  #pragma unroll
  for (int i = 0; i < 4; ++i) { m[i] = -1e30f; s[i] = 0.f; bi[i] = 0x7fffffff; }

  // cooperative DMA of one 8 KB tile: wave w issues chunks 2w, 2w+1
  auto dma = [&](int T, int bufi) {
    #pragma unroll
    for (int c = 0; c < 2; ++c) {
      const int chunk = wid * 2 + c;
      const ushort* src = Asw + ((size_t)T * 8 + chunk) * 512 + (size_t)lane * 8;
      __builtin_amdgcn_global_load_lds(
          (const __attribute__((address_space(1))) void*)src,
          (__attribute__((address_space(3))) void*)(&sB[bufi][chunk * 512]),
          16, 0, 0);
    }
  };

  dma(T0, 0);
  __syncthreads();                                 // tile 0 resident

  #pragma unroll 1
  for (int t = 0; t < NTB; ++t) {
    if (t + 1 < NTB) dma(T0 + t + 1, (t + 1) & 1);
    const ushort* B = sB[t & 1];
    f32x4 c0 = {0.f, 0.f, 0.f, 0.f};
    #pragma unroll
    for (int kk = 0; kk < 8; ++kk) {
      bf16x8 b = *(const bf16x8*)(B + kk * 512 + lane * 8);
      c0 = __builtin_amdgcn_mfma_f32_16x16x32_bf16(af[kk], b, c0, 0, 0, 0);
    }
    const int   colIdx = (T0 + t) * 16 + lcol;
    const float cbv    = cb[colIdx];               // 64-B broadcast segment
    #pragma unroll
    for (int i = 0; i < 4; ++i) {
      float v2 = fmaf(c0[i], 2.f * L2E, cbv);      // log2-frame shifted logit
      float dv = v2 - m[i];
      bool  gt = dv > 0.f;
      float e  = exp2f(-fabsf(dv));                // single non-unit exp factor
      s[i]  = fmaf(s[i], gt ? e : 1.f, gt ? 1.f : e);
      m[i]  = fmaxf(m[i], v2);
      bi[i] = gt ? colIdx : bi[i];                 // strict >: first max wins
    }
    __syncthreads();                               // drain DMA; guard overwrite
  }

  // merge across the 16 lanes sharing rows (cols differ)
  #pragma unroll
  for (int mask = 1; mask < 16; mask <<= 1) {
    #pragma unroll
    for (int i = 0; i < 4; ++i) {
      float om = __shfl_xor(m[i], mask);
      float os = __shfl_xor(s[i], mask);
      int   oi = __shfl_xor(bi[i], mask);
      float nm = fmaxf(m[i], om);
      s[i] = s[i] * exp2f(m[i] - nm) + os * exp2f(om - nm);
      bool better = (om > m[i]) || (om == m[i] && oi < bi[i]);
      bi[i] = better ? oi : bi[i];
      m[i]  = nm;
    }
  }

  // post this quarter's per-row partials (device-scope atomics), then arrive
  if (lcol == 0) {
    #pragma unroll
    for (int i = 0; i < 4; ++i) {
      const int row = r0 + wid * 16 + quad * 4 + i;
      atomicExch(&pm[qq * NROW + row], m[i]);
      atomicExch(&ps[qq * NROW + row], s[i]);
      atomicExch(&pb[qq * NROW + row], bi[i]);
    }
    __threadfence();
  }
  __syncthreads();
  if (tid == 0) s_old = atomicAdd(&rgcount[rg], 1);
  __syncthreads();
  if (s_old != 3) return;                          // only the LAST arriver merges

  // label-logit post-pass: 4 lanes per row (64 rows); bf16 dot with the same
  // rounding as the MFMA path.
  {
    const int rl = tid >> 2, l = tid & 3;
    const int row = r0 + rl;
    const int lab = label[row >> 3];
    float dot = 0.f;
    #pragma unroll
    for (int c = 0; c < 2; ++c) {
      const int kk = l * 2 + c;
      const size_t qc = ((size_t)(row >> 4) * 8 + kk) * 64 + (row & 15);
      const size_t ac = ((size_t)(lab >> 4) * 8 + kk) * 64 + (lab & 15);
      #pragma unroll
      for (int qd = 0; qd < 4; ++qd) {
        bf16x8 qv = qb[qc + qd * 16];
        bf16x8 av = bb[ac + qd * 16];
        #pragma unroll
        for (int j = 0; j < 8; ++j) dot = fmaf(bf2f(qv[j]), bf2f(av[j]), dot);
      }
    }
    dot += __shfl_xor(dot, 1);
    dot += __shfl_xor(dot, 2);
    if (l == 0) slab[rl] = fmaf(dot, 2.f * L2E, cb[lab]);  // shifted label logit
  }
  __syncthreads();

  if (tid < 64) {
    const int row = r0 + tid;
    float mm = -1e30f, sv = 0.f;
    int   b  = 0x7fffffff;
    #pragma unroll
    for (int k = 0; k < 4; ++k) {                  // quarters in ascending col order
      float om = atomicAdd(&pm[k * NROW + row], 0.f);   // coherent reads
      float os = atomicAdd(&ps[k * NROW + row], 0.f);
      int   oi = atomicAdd(&pb[k * NROW + row], 0);
      float nm = fmaxf(mm, om);
      sv = sv * exp2f(mm - nm) + os * exp2f(om - nm);
      bool better = (om > mm) || (om == mm && oi < b);
      b = better ? oi : b;
      mm = nm;
    }
    const int lb = label[row >> 3];
    float loss = LN2 * (mm + log2f(sv) - slab[tid]);
    float corr = (b == lb) ? 1.f : 0.f;
    #pragma unroll
    for (int mask = 32; mask; mask >>= 1) {        // tid<64 = one full wave
      loss += __shfl_xor(loss, mask);
      corr += __shfl_xor(corr, mask);
    }
    if (tid == 0) {
      atomicAdd(&accum[0], loss);
      atomicAdd(&accum[1], corr);
      __threadfence();
      if (atomicAdd(fincount, 1) == NRG - 1) {
        out[0] = atomicAdd(&accum[0], 0.f) / (float)NROW;   // coherent reads
        out[1] = atomicAdd(&accum[1], 0.f) * 100.f / (float)NROW;
      }
    }
  }
}

// ---------------------------------------------------------------------------
extern "C" void kernel_launch(void* const* d_in, const int* in_sizes, int n_in,
                              void* d_out, int out_size, void* d_ws, size_t ws_size,
                              hipStream_t stream) {
  const float* x     = (const float*)d_in[0];
  const int*   label = (const int*)d_in[1];
  float* out = (float*)d_out;

  // ws layout (float-sized slots): [0:2) accum | [2] fincount |
  // [16,16+NRG) rgcount | cb[NCOL] | pm[4*NROW] | ps[4*NROW] |
  // pb[4*NROW] (int) | Asw (NCOL*DD ushort) | Qsw (NROW*DD ushort)
  float*  W        = (float*)d_ws;
  float*  accum    = W;
  int*    fincount = (int*)(W + 2);
  int*    rgcount  = (int*)(W + 16);
  float*  cb       = W + 16 + NRG;
  float*  pm       = cb + NCOL;
  float*  ps       = pm + 4 * NROW;
  int*    pb       = (int*)(ps + 4 * NROW);
  ushort* Asw      = (ushort*)(pb + 4 * NROW);
  ushort* Qsw      = Asw + (size_t)NCOL * DD;

  hipLaunchKernelGGL(proto_prep, dim3(NEP / 4), dim3(256), 0, stream,
                     x, cb, Asw, Qsw, accum, fincount, rgcount);
  hipLaunchKernelGGL(proto_main, dim3(NRG * 4), dim3(256), 0, stream,
                     Qsw, Asw, cb, label, pm, ps, pb, rgcount,
                     accum, fincount, out);
}

// Round 12
// 147.730 us; speedup vs baseline: 1.2616x; 1.2616x over previous
//
#include <hip/hip_runtime.h>
#include <math.h>

#define EPS  1e-6f
#define DD   256
#define NSUP 5
#define NQ   8
#define SEQ  13
#define L2E  1.44269504088896f
#define LN2  0.693147180559945f
#define NEP  2048            // episodes
#define NROW 16384           // NEP*NQ query rows
#define NCOL 2048            // anchor columns
#define NRG  128             // rowgroups of 128 rows
#define NTB  32              // col-tiles per block (512-col quarter)

typedef short bf16x8 __attribute__((ext_vector_type(8)));
typedef unsigned short u16x4 __attribute__((ext_vector_type(4)));
typedef float f32x4  __attribute__((ext_vector_type(4)));

__device__ __forceinline__ ushort f2bf(float f) {
  union { float f; unsigned u; } v; v.f = f;
  unsigned r = v.u + 0x7FFFu + ((v.u >> 16) & 1u);   // round-to-nearest-even
  return (ushort)(r >> 16);
}
__device__ __forceinline__ float bf2f(short u) {
  union { unsigned u; float f; } v; v.u = ((unsigned)(unsigned short)u) << 16;
  return v.f;
}

// ---------------------------------------------------------------------------
// prep (r8-proven): anchors/queries in MFMA-fragment-SWIZZLED order; element
// (c,d) -> ushort idx (((c>>4)*8+(d>>5))*64 + ((d>>3)&3)*16 + (c&15))*8+(d&7).
// cb[c] = -log2(e)*(sum(a^2) - 2*eps*sum(a)); row-constant cq cancels.
// Zeroes accum/fincount/rgcount (ws is re-poisoned before every call).
// ---------------------------------------------------------------------------
__global__ __launch_bounds__(256) void proto_prep(
    const float* __restrict__ x, float* __restrict__ cb,
    ushort* __restrict__ Asw, ushort* __restrict__ Qsw,
    float* __restrict__ accum, int* __restrict__ fincount,
    int* __restrict__ rgcount) {
  const int tid = threadIdx.x, g = tid >> 6, l = tid & 63;
  const int n = blockIdx.x * 4 + g;
  if (blockIdx.x == 0 && tid == 0) { accum[0] = 0.f; accum[1] = 0.f; fincount[0] = 0; }
  if (tid == 0 && blockIdx.x < NRG) rgcount[blockIdx.x] = 0;

  const float4* xr4 = (const float4*)(x + (size_t)n * SEQ * DD);

  const int d0   = l * 4;
  const int kk   = d0 >> 5, quad = (d0 >> 3) & 3, j = d0 & 7;   // j in {0,4}
  const size_t chunk_d = (size_t)kk * 64 + (size_t)quad * 16;

  float4 a = {0.f, 0.f, 0.f, 0.f};
  #pragma unroll
  for (int s = 0; s < NSUP; ++s) {
    float4 v = xr4[s * 64 + l];
    a.x += v.x; a.y += v.y; a.z += v.z; a.w += v.w;
  }
  a.x *= 0.2f; a.y *= 0.2f; a.z *= 0.2f; a.w *= 0.2f;
  {
    const size_t idx = (((size_t)(n >> 4) * 8) * 64 + chunk_d + (n & 15)) * 8 + j;
    u16x4 o = {f2bf(a.x), f2bf(a.y), f2bf(a.z), f2bf(a.w)};
    *(u16x4*)(Asw + idx) = o;
  }
  float s1 = a.x + a.y + a.z + a.w;
  float s2 = a.x * a.x + a.y * a.y + a.z * a.z + a.w * a.w;
  #pragma unroll
  for (int off = 32; off; off >>= 1) {
    s1 += __shfl_xor(s1, off);
    s2 += __shfl_xor(s2, off);
  }
  if (l == 0) cb[n] = -L2E * (s2 - 2.f * EPS * s1);

  #pragma unroll
  for (int s = 0; s < NQ; ++s) {
    float4 q = xr4[(NSUP + s) * 64 + l];
    const int row = n * NQ + s;
    const size_t idx = (((size_t)(row >> 4) * 8) * 64 + chunk_d + (row & 15)) * 8 + j;
    u16x4 o = {f2bf(q.x), f2bf(q.y), f2bf(q.z), f2bf(q.w)};
    *(u16x4*)(Qsw + idx) = o;
  }
}

// ---------------------------------------------------------------------------
// main: cooperative LDS staging at FIXED granularity. 512 blocks x 256
// threads; block = rowgroup (128 rows) x col-quarter (512 cols = 32 tiles).
// Wave w owns rows [r0+32w, +32) = 2 MFMA row-sets, so each LDS tile feeds 8
// row-sets (B L2 traffic /8 vs per-wave staging). K-loop processes tiles in
// PAIRS: dma(pair p+1) -> compute 2 tiles (32 MFMA + 2 epilogues per wave,
// ~520 cyc) -> ONE barrier. r11 failed at 8 MFMA/barrier; this is 4x that.
// ~35 KB LDS, no min-waves bound (r5/r6: min-waves>=3 clamps VGPR to 64 and
// spills 79 MB) -> 2 blocks/CU co-reside, barrier drains overlap.
// cb staged in LDS so K-loop VMEM is pure DMA. Quarter partials via
// device-scope atomics; LAST arriver (rgcount==3) merges quarters in
// ascending col order, computes label logits (bf16 dot, same rounding),
// accumulates; counter finalize (r11-proven machinery).
// MFMA layouts (verified): A m=lane&15,k=quad*8+j ; B n=lane&15,k=quad*8+j ;
// C col=lane&15,row=quad*4+reg.
// ---------------------------------------------------------------------------
__global__ __launch_bounds__(256) void proto_main(
    const ushort* __restrict__ Qsw, const ushort* __restrict__ Asw,
    const float* __restrict__ cb, const int* __restrict__ label,
    float* __restrict__ pm, float* __restrict__ ps, int* __restrict__ pb,
    int* __restrict__ rgcount,
    float* __restrict__ accum, int* __restrict__ fincount,
    float* __restrict__ out) {
  const int tid  = threadIdx.x;
  const int wid  = tid >> 6, lane = tid & 63;
  const int quad = lane >> 4, lcol = lane & 15;
  const int rg   = blockIdx.x >> 2;
  const int qq   = blockIdx.x & 3;
  const int r0   = rg * 128;
  const int T0   = qq * NTB;

  __shared__ __align__(16) ushort sB[2][8192];   // 2 x 16 KB (tile pairs)
  __shared__ float scb[512];
  __shared__ float slab[128];
  __shared__ float sred[2][2];
  __shared__ int   s_old;

  const bf16x8* qb = (const bf16x8*)Qsw;
  const bf16x8* bb = (const bf16x8*)Asw;

  // stage this quarter's cb into LDS (K-loop VMEM stays pure DMA)
  scb[tid]       = cb[T0 * 16 + tid];
  scb[tid + 256] = cb[T0 * 16 + tid + 256];

  // A fragments: wave w covers rows r0+32w..+31 = row-tiles 2w, 2w+1
  bf16x8 af[2][8];
  #pragma unroll
  for (int set = 0; set < 2; ++set) {
    const size_t base = ((size_t)((r0 >> 4) + wid * 2 + set) * 8) * 64 + lane;
    #pragma unroll
    for (int kk = 0; kk < 8; ++kk) af[set][kk] = qb[base + (size_t)kk * 64];
  }

  float m[2][4], s[2][4];
  int   bi[2][4];
  #pragma unroll
  for (int set = 0; set < 2; ++set)
    #pragma unroll
    for (int i = 0; i < 4; ++i) {
      m[set][i] = -1e30f; s[set][i] = 0.f; bi[set][i] = 0x7fffffff;
    }

  // cooperative DMA of one 16 KB tile-pair: wave w issues chunks 4w..4w+3
  auto dma = [&](int p, int bufi) {
    #pragma unroll
    for (int c = 0; c < 4; ++c) {
      const int chunk = wid * 4 + c;                 // 0..15
      const int tile  = 2 * p + (chunk >> 3);
      const int kk    = chunk & 7;
      const ushort* src = Asw + ((size_t)(T0 + tile) * 8 + kk) * 512
                        + (size_t)lane * 8;
      __builtin_amdgcn_global_load_lds(
          (const __attribute__((address_space(1))) void*)src,
          (__attribute__((address_space(3))) void*)(&sB[bufi][chunk * 512]),
          16, 0, 0);
    }
  };

  dma(0, 0);
  __syncthreads();                                   // pair 0 resident

  #pragma unroll 1
  for (int p = 0; p < 16; ++p) {
    if (p + 1 < 16) dma(p + 1, (p + 1) & 1);
    #pragma unroll
    for (int tt = 0; tt < 2; ++tt) {
      const ushort* B = &sB[p & 1][tt * 4096];
      f32x4 c0 = {0.f, 0.f, 0.f, 0.f}, c1 = {0.f, 0.f, 0.f, 0.f};
      #pragma unroll
      for (int kk = 0; kk < 8; ++kk) {
        bf16x8 b = *(const bf16x8*)(B + kk * 512 + lane * 8);
        c0 = __builtin_amdgcn_mfma_f32_16x16x32_bf16(af[0][kk], b, c0, 0, 0, 0);
        c1 = __builtin_amdgcn_mfma_f32_16x16x32_bf16(af[1][kk], b, c1, 0, 0, 0);
      }
      const int   lt     = 2 * p + tt;
      const int   colIdx = (T0 + lt) * 16 + lcol;
      const float cbv    = scb[lt * 16 + lcol];
      #pragma unroll
      for (int set = 0; set < 2; ++set) {
        #pragma unroll
        for (int i = 0; i < 4; ++i) {
          float cv = (set == 0) ? c0[i] : c1[i];
          float v2 = fmaf(cv, 2.f * L2E, cbv);       // log2-frame shifted logit
          float dv = v2 - m[set][i];
          bool  gt = dv > 0.f;
          float e  = exp2f(-fabsf(dv));              // single non-unit factor
          s[set][i]  = fmaf(s[set][i], gt ? e : 1.f, gt ? 1.f : e);
          m[set][i]  = fmaxf(m[set][i], v2);
          bi[set][i] = gt ? colIdx : bi[set][i];     // strict >: first max wins
        }
      }
    }
    __syncthreads();                                 // drain DMA; guard reuse
  }

  // merge across the 16 lanes sharing rows (cols differ)
  #pragma unroll
  for (int mask = 1; mask < 16; mask <<= 1) {
    #pragma unroll
    for (int set = 0; set < 2; ++set)
      #pragma unroll
      for (int i = 0; i < 4; ++i) {
        float om = __shfl_xor(m[set][i], mask);
        float os = __shfl_xor(s[set][i], mask);
        int   oi = __shfl_xor(bi[set][i], mask);
        float nm = fmaxf(m[set][i], om);
        s[set][i] = s[set][i] * exp2f(m[set][i] - nm) + os * exp2f(om - nm);
        bool better = (om > m[set][i]) || (om == m[set][i] && oi < bi[set][i]);
        bi[set][i] = better ? oi : bi[set][i];
        m[set][i]  = nm;
      }
  }

  // post this quarter's per-row partials (device-scope atomics), then arrive
  if (lcol == 0) {
    #pragma unroll
    for (int set = 0; set < 2; ++set)
      #pragma unroll
      for (int i = 0; i < 4; ++i) {
        const int row = r0 + wid * 32 + set * 16 + quad * 4 + i;
        atomicExch(&pm[qq * NROW + row], m[set][i]);
        atomicExch(&ps[qq * NROW + row], s[set][i]);
        atomicExch(&pb[qq * NROW + row], bi[set][i]);
      }
    __threadfence();
  }
  __syncthreads();
  if (tid == 0) s_old = atomicAdd(&rgcount[rg], 1);
  __syncthreads();
  if (s_old != 3) return;                            // only the LAST arriver merges

  // label-logit post-pass: 2 lanes per row (128 rows); bf16 dot with the
  // same rounding as the MFMA path (r6-r11 proven pattern).
  {
    const int rl = tid >> 1, l = tid & 1;
    const int row = r0 + rl;
    const int lab = label[row >> 3];
    float dot = 0.f;
    #pragma unroll
    for (int c = 0; c < 4; ++c) {
      const int kk = l * 4 + c;
      const size_t qc = ((size_t)(row >> 4) * 8 + kk) * 64 + (row & 15);
      const size_t ac = ((size_t)(lab >> 4) * 8 + kk) * 64 + (lab & 15);
      #pragma unroll
      for (int qd = 0; qd < 4; ++qd) {
        bf16x8 qv = qb[qc + qd * 16];
        bf16x8 av = bb[ac + qd * 16];
        #pragma unroll
        for (int j = 0; j < 8; ++j) dot = fmaf(bf2f(qv[j]), bf2f(av[j]), dot);
      }
    }
    dot += __shfl_xor(dot, 1);
    if (l == 0) slab[rl] = fmaf(dot, 2.f * L2E, cb[lab]);  // shifted label logit
  }
  __syncthreads();

  float loss = 0.f, corr = 0.f;
  if (tid < 128) {                                   // waves 0 and 1
    const int row = r0 + tid;
    float mm = -1e30f, sv = 0.f;
    int   b  = 0x7fffffff;
    #pragma unroll
    for (int k = 0; k < 4; ++k) {                    // quarters ascending
      float om = atomicAdd(&pm[k * NROW + row], 0.f);   // coherent reads
      float os = atomicAdd(&ps[k * NROW + row], 0.f);
      int   oi = atomicAdd(&pb[k * NROW + row], 0);
      float nm = fmaxf(mm, om);
      sv = sv * exp2f(mm - nm) + os * exp2f(om - nm);
      bool better = (om > mm) || (om == mm && oi < b);
      b = better ? oi : b;
      mm = nm;
    }
    const int lb = label[row >> 3];
    loss = LN2 * (mm + log2f(sv) - slab[tid]);
    corr = (b == lb) ? 1.f : 0.f;
    #pragma unroll
    for (int mask = 32; mask; mask >>= 1) {          // full-wave xor reduce
      loss += __shfl_xor(loss, mask);
      corr += __shfl_xor(corr, mask);
    }
    if (lane == 0) { sred[wid][0] = loss; sred[wid][1] = corr; }
  }
  __syncthreads();
  if (tid == 0) {
    atomicAdd(&accum[0], sred[0][0] + sred[1][0]);
    atomicAdd(&accum[1], sred[0][1] + sred[1][1]);
    __threadfence();
    if (atomicAdd(fincount, 1) == NRG - 1) {
      out[0] = atomicAdd(&accum[0], 0.f) / (float)NROW;   // coherent reads
      out[1] = atomicAdd(&accum[1], 0.f) * 100.f / (float)NROW;
    }
  }
}

// ---------------------------------------------------------------------------
extern "C" void kernel_launch(void* const* d_in, const int* in_sizes, int n_in,
                              void* d_out, int out_size, void* d_ws, size_t ws_size,
                              hipStream_t stream) {
  const float* x     = (const float*)d_in[0];
  const int*   label = (const int*)d_in[1];
  float* out = (float*)d_out;

  // ws layout (float-sized slots): [0:2) accum | [2] fincount |
  // [16,16+NRG) rgcount | cb[NCOL] | pm[4*NROW] | ps[4*NROW] |
  // pb[4*NROW] (int) | Asw (NCOL*DD ushort) | Qsw (NROW*DD ushort)
  float*  W        = (float*)d_ws;
  float*  accum    = W;
  int*    fincount = (int*)(W + 2);
  int*    rgcount  = (int*)(W + 16);
  float*  cb       = W + 16 + NRG;
  float*  pm       = cb + NCOL;
  float*  ps       = pm + 4 * NROW;
  int*    pb       = (int*)(ps + 4 * NROW);
  ushort* Asw      = (ushort*)(pb + 4 * NROW);
  ushort* Qsw      = Asw + (size_t)NCOL * DD;

  hipLaunchKernelGGL(proto_prep, dim3(NEP / 4), dim3(256), 0, stream,
                     x, cb, Asw, Qsw, accum, fincount, rgcount);
  hipLaunchKernelGGL(proto_main, dim3(NRG * 4), dim3(256), 0, stream,
                     Qsw, Asw, cb, label, pm, ps, pb, rgcount,
                     accum, fincount, out);
}

// Round 13
// 122.585 us; speedup vs baseline: 1.5204x; 1.2051x over previous
//
#include <hip/hip_runtime.h>
#include <math.h>

#define EPS  1e-6f
#define DD   256
#define NSUP 5
#define NQ   8
#define SEQ  13
#define L2E  1.44269504088896f
#define LN2  0.693147180559945f
#define NEP  2048            // episodes
#define NROW 16384           // NEP*NQ query rows
#define NCOL 2048            // anchor columns

typedef short bf16x8 __attribute__((ext_vector_type(8)));
typedef unsigned short u16x4 __attribute__((ext_vector_type(4)));
typedef float f32x4  __attribute__((ext_vector_type(4)));

__device__ __forceinline__ ushort f2bf(float f) {
  union { float f; unsigned u; } v; v.f = f;
  unsigned r = v.u + 0x7FFFu + ((v.u >> 16) & 1u);   // round-to-nearest-even
  return (ushort)(r >> 16);
}
__device__ __forceinline__ float bf2f(short u) {
  union { unsigned u; float f; } v; v.u = ((unsigned)(unsigned short)u) << 16;
  return v.f;
}

// ---------------------------------------------------------------------------
// prep (r8-proven): anchors/queries in MFMA-fragment-SWIZZLED order; element
// (c,d) -> ushort idx (((c>>4)*8+(d>>5))*64 + ((d>>3)&3)*16 + (c&15))*8+(d&7).
// cb[c] = -log2(e)*(sum(a^2) - 2*eps*sum(a)); row-constant cq cancels.
// Zeroes accum/fincount (ws is re-poisoned before every call).
// ---------------------------------------------------------------------------
__global__ __launch_bounds__(256) void proto_prep(
    const float* __restrict__ x, float* __restrict__ cb,
    ushort* __restrict__ Asw, ushort* __restrict__ Qsw,
    float* __restrict__ accum, int* __restrict__ fincount) {
  const int tid = threadIdx.x, g = tid >> 6, l = tid & 63;
  const int n = blockIdx.x * 4 + g;
  if (blockIdx.x == 0 && tid == 0) { accum[0] = 0.f; accum[1] = 0.f; fincount[0] = 0; }

  const float4* xr4 = (const float4*)(x + (size_t)n * SEQ * DD);

  const int d0   = l * 4;
  const int kk   = d0 >> 5, quad = (d0 >> 3) & 3, j = d0 & 7;   // j in {0,4}
  const size_t chunk_d = (size_t)kk * 64 + (size_t)quad * 16;

  float4 a = {0.f, 0.f, 0.f, 0.f};
  #pragma unroll
  for (int s = 0; s < NSUP; ++s) {
    float4 v = xr4[s * 64 + l];
    a.x += v.x; a.y += v.y; a.z += v.z; a.w += v.w;
  }
  a.x *= 0.2f; a.y *= 0.2f; a.z *= 0.2f; a.w *= 0.2f;
  {
    const size_t idx = (((size_t)(n >> 4) * 8) * 64 + chunk_d + (n & 15)) * 8 + j;
    u16x4 o = {f2bf(a.x), f2bf(a.y), f2bf(a.z), f2bf(a.w)};
    *(u16x4*)(Asw + idx) = o;
  }
  float s1 = a.x + a.y + a.z + a.w;
  float s2 = a.x * a.x + a.y * a.y + a.z * a.z + a.w * a.w;
  #pragma unroll
  for (int off = 32; off; off >>= 1) {
    s1 += __shfl_xor(s1, off);
    s2 += __shfl_xor(s2, off);
  }
  if (l == 0) cb[n] = -L2E * (s2 - 2.f * EPS * s1);

  #pragma unroll
  for (int s = 0; s < NQ; ++s) {
    float4 q = xr4[(NSUP + s) * 64 + l];
    const int row = n * NQ + s;
    const size_t idx = (((size_t)(row >> 4) * 8) * 64 + chunk_d + (row & 15)) * 8 + j;
    u16x4 o = {f2bf(q.x), f2bf(q.y), f2bf(q.z), f2bf(q.w)};
    *(u16x4*)(Qsw + idx) = o;
  }
}

// ---------------------------------------------------------------------------
// main: 256 blocks x 256 threads (1 block/CU, 1 wave/SIMD — all we ever
// effectively got). Block = 64 rows x ALL 2048 cols; wave w = 512-col stripe
// (32 tiles) x 4 MFMA row-sets (af[4][8] = 128 VGPR). __launch_bounds__(256,1)
// grants up to 512 VGPR/wave, so the ping-pong prefetch is finally REAL (r4-
// r12: 88-92 VGPR budget silently collapsed prefetch into load->use,
// exposing ~300 cyc L2 latency per tile — the shared ~520 cyc/tile plateau).
// Per tile: 32 MFMA in 4 independent chains + 16 slot updates (~640 cyc busy)
// >> load latency. Single pass over cols -> no cross-block partials; r8 LDS
// stripe-merge extended to 64 rows; r11-proven 4-lane/row label-logit dot.
// MFMA layouts (verified): A m=lane&15,k=quad*8+j ; B n=lane&15,k=quad*8+j ;
// C col=lane&15,row=quad*4+reg.
// ---------------------------------------------------------------------------
__global__ __launch_bounds__(256, 1) void proto_main(
    const ushort* __restrict__ Qsw, const ushort* __restrict__ Asw,
    const float* __restrict__ cb, const int* __restrict__ label,
    float* __restrict__ accum, int* __restrict__ fincount,
    float* __restrict__ out) {
  const int tid  = threadIdx.x;
  const int wid  = tid >> 6, lane = tid & 63;
  const int quad = lane >> 4, lcol = lane & 15;
  const int r0   = blockIdx.x * 64;

  const bf16x8* qb = (const bf16x8*)Qsw;
  const bf16x8* bb = (const bf16x8*)Asw;

  // resident A fragments: 4 row-sets x 8 K-chunks (coalesced loads)
  bf16x8 af[4][8];
  #pragma unroll
  for (int set = 0; set < 4; ++set) {
    const size_t base = ((size_t)((r0 >> 4) + set) * 8) * 64 + lane;
    #pragma unroll
    for (int kk = 0; kk < 8; ++kk) af[set][kk] = qb[base + (size_t)kk * 64];
  }

  float m[4][4], s[4][4];
  int   bi[4][4];
  #pragma unroll
  for (int set = 0; set < 4; ++set)
    #pragma unroll
    for (int i = 0; i < 4; ++i) {
      m[set][i] = -1e30f; s[set][i] = 0.f; bi[set][i] = 0x7fffffff;
    }

  auto process = [&](int T, bf16x8* B) {
    f32x4 c0 = {0.f, 0.f, 0.f, 0.f}, c1 = {0.f, 0.f, 0.f, 0.f};
    f32x4 c2 = {0.f, 0.f, 0.f, 0.f}, c3 = {0.f, 0.f, 0.f, 0.f};
    #pragma unroll
    for (int kk = 0; kk < 8; ++kk) {
      c0 = __builtin_amdgcn_mfma_f32_16x16x32_bf16(af[0][kk], B[kk], c0, 0, 0, 0);
      c1 = __builtin_amdgcn_mfma_f32_16x16x32_bf16(af[1][kk], B[kk], c1, 0, 0, 0);
      c2 = __builtin_amdgcn_mfma_f32_16x16x32_bf16(af[2][kk], B[kk], c2, 0, 0, 0);
      c3 = __builtin_amdgcn_mfma_f32_16x16x32_bf16(af[3][kk], B[kk], c3, 0, 0, 0);
    }
    const int   colIdx = T * 16 + lcol;
    const float cbv    = cb[colIdx];       // 64-B broadcast segment
    #pragma unroll
    for (int set = 0; set < 4; ++set) {
      #pragma unroll
      for (int i = 0; i < 4; ++i) {
        float cv = (set == 0) ? c0[i] : (set == 1) ? c1[i]
                 : (set == 2) ? c2[i] : c3[i];
        float v2 = fmaf(cv, 2.f * L2E, cbv);     // log2-frame shifted logit
        float dv = v2 - m[set][i];
        bool  gt = dv > 0.f;
        float e  = exp2f(-fabsf(dv));            // single non-unit exp factor
        s[set][i]  = fmaf(s[set][i], gt ? e : 1.f, gt ? 1.f : e);
        m[set][i]  = fmaxf(m[set][i], v2);
        bi[set][i] = gt ? colIdx : bi[set][i];   // strict >: first max wins
      }
    }
  };

  const int T0 = wid * 32;
  bf16x8 buf0[8], buf1[8];
  #pragma unroll
  for (int kk = 0; kk < 8; ++kk)
    buf0[kk] = bb[((size_t)T0 * 8 + (size_t)kk) * 64 + lane];

  #pragma unroll 1
  for (int t = 0; t < 32; t += 2) {
    {
      const int Tn = T0 + t + 1;                             // always valid
      #pragma unroll
      for (int kk = 0; kk < 8; ++kk)
        buf1[kk] = bb[((size_t)Tn * 8 + (size_t)kk) * 64 + lane];
    }
    process(T0 + t, buf0);
    {
      const int Tm = (t + 2 < 32) ? T0 + t + 2 : T0 + t + 1; // clamp tail
      #pragma unroll
      for (int kk = 0; kk < 8; ++kk)
        buf0[kk] = bb[((size_t)Tm * 8 + (size_t)kk) * 64 + lane];
    }
    process(T0 + t + 1, buf1);
  }

  // merge across the 16 lanes sharing rows (cols differ)
  #pragma unroll
  for (int mask = 1; mask < 16; mask <<= 1) {
    #pragma unroll
    for (int set = 0; set < 4; ++set)
      #pragma unroll
      for (int i = 0; i < 4; ++i) {
        float om = __shfl_xor(m[set][i], mask);
        float os = __shfl_xor(s[set][i], mask);
        int   oi = __shfl_xor(bi[set][i], mask);
        float nm = fmaxf(m[set][i], om);
        s[set][i] = s[set][i] * exp2f(m[set][i] - nm) + os * exp2f(om - nm);
        bool better = (om > m[set][i]) || (om == m[set][i] && oi < bi[set][i]);
        bi[set][i] = better ? oi : bi[set][i];
        m[set][i]  = nm;
      }
  }

  __shared__ float sm[4][64], ssh[4][64], slab[64];
  __shared__ int   sbi[4][64];
  if (lcol == 0) {
    #pragma unroll
    for (int set = 0; set < 4; ++set)
      #pragma unroll
      for (int i = 0; i < 4; ++i) {
        int rl = set * 16 + quad * 4 + i;
        sm[wid][rl] = m[set][i]; ssh[wid][rl] = s[set][i]; sbi[wid][rl] = bi[set][i];
      }
  }

  // label-logit post-pass (r11-proven): 4 lanes per row (64 rows); bf16 dot
  // with the same rounding as the MFMA path.
  {
    const int rl = tid >> 2, l = tid & 3;
    const int row = r0 + rl;
    const int lab = label[row >> 3];
    float dot = 0.f;
    #pragma unroll
    for (int c = 0; c < 2; ++c) {
      const int kk = l * 2 + c;
      const size_t qc = ((size_t)(row >> 4) * 8 + kk) * 64 + (row & 15);
      const size_t ac = ((size_t)(lab >> 4) * 8 + kk) * 64 + (lab & 15);
      #pragma unroll
      for (int qd = 0; qd < 4; ++qd) {
        bf16x8 qv = qb[qc + qd * 16];
        bf16x8 av = bb[ac + qd * 16];
        #pragma unroll
        for (int j = 0; j < 8; ++j) dot = fmaf(bf2f(qv[j]), bf2f(av[j]), dot);
      }
    }
    dot += __shfl_xor(dot, 1);
    dot += __shfl_xor(dot, 2);
    if (l == 0) slab[rl] = fmaf(dot, 2.f * L2E, cb[lab]);  // shifted label logit
  }
  __syncthreads();

  if (tid < 64) {                                  // one full wave
    float mm = sm[0][tid], sv = ssh[0][tid];
    int   b  = sbi[0][tid];
    #pragma unroll
    for (int w = 1; w < 4; ++w) {                  // stripes in ascending col order
      float om = sm[w][tid], os = ssh[w][tid];
      int   oi = sbi[w][tid];
      float nm = fmaxf(mm, om);
      sv = sv * exp2f(mm - nm) + os * exp2f(om - nm);
      bool better = (om > mm) || (om == mm && oi < b);
      b = better ? oi : b;
      mm = nm;
    }
    const int row = r0 + tid;
    const int lb  = label[row >> 3];
    float loss = LN2 * (mm + log2f(sv) - slab[tid]);
    float corr = (b == lb) ? 1.f : 0.f;
    #pragma unroll
    for (int mask = 32; mask; mask >>= 1) {        // full-wave xor reduce
      loss += __shfl_xor(loss, mask);
      corr += __shfl_xor(corr, mask);
    }
    if (tid == 0) {
      atomicAdd(&accum[0], loss);
      atomicAdd(&accum[1], corr);
      __threadfence();
      if (atomicAdd(fincount, 1) == (int)gridDim.x - 1) {
        out[0] = atomicAdd(&accum[0], 0.f) / (float)NROW;   // coherent reads
        out[1] = atomicAdd(&accum[1], 0.f) * 100.f / (float)NROW;
      }
    }
  }
}

// ---------------------------------------------------------------------------
extern "C" void kernel_launch(void* const* d_in, const int* in_sizes, int n_in,
                              void* d_out, int out_size, void* d_ws, size_t ws_size,
                              hipStream_t stream) {
  const float* x     = (const float*)d_in[0];
  const int*   label = (const int*)d_in[1];
  float* out = (float*)d_out;

  // ws layout (float-sized slots): [0:2) accum | [2] fincount |
  // [16,16+NCOL) cb | Asw (NCOL*DD ushort) | Qsw (NROW*DD ushort)
  float*  W        = (float*)d_ws;
  float*  accum    = W;
  int*    fincount = (int*)(W + 2);
  float*  cb       = W + 16;
  ushort* Asw      = (ushort*)(cb + NCOL);
  ushort* Qsw      = Asw + (size_t)NCOL * DD;

  hipLaunchKernelGGL(proto_prep, dim3(NEP / 4), dim3(256), 0, stream,
                     x, cb, Asw, Qsw, accum, fincount);
  hipLaunchKernelGGL(proto_main, dim3(NROW / 64), dim3(256), 0, stream,
                     Qsw, Asw, cb, label, accum, fincount, out);
}